// Round 8
// baseline (281.263 us; speedup 1.0000x reference)
//
#include <hip/hip_runtime.h>
#include <stdint.h>

// CrossNetwork fused: x:[16384,512] f32, W:[4,512,512] f32, b:[4,512] f32
// out:[16384,2048] f32 = concat(x1..x4).
//
// Algebra: residual loop collapses to x_eff = x_l + c_l*1 with
//   c = 0; for j<l: c = c + dot(x_l,x_j) + c*sum(x_j)
// and (x_l + c*1)@W^T = x_l@W^T + c*rowsum(W).
//
// R10 = R8 structure + two fixes aimed at the measured anomalies:
//  1) amdgpu_waves_per_eu(4,4): R8/R9 both allocated only 64 VGPRs for the
//     1024-thread block (default heuristic targets 8 waves/EU) and
//     __launch_bounds__(1024,4) did NOT raise it. Clamp to 4 waves/EU ->
//     128-reg budget; per-thread state (~100) fits without spill.
//  2) Coalesced out-writes via LDS staging: the old epilogue wrote out as
//     16 scattered 4B stores/thread -> partial-line RFO fetches (~80MB) and
//     dirty-line write amplification (~94MB), matching the counter excess.
//     Now each 32-row half-tile is written to a 64KB sOut (overlaying the
//     sB double-buffer, dead during the epilogue) and streamed out as
//     full-line float4 stores (1KB/wave/instr). B-staging is confined
//     within a layer; the next layer's first tile is staged at epilogue end.
// Grid: 256 blocks (1/CU) x 1024 threads (16 waves = 2 wm x 8 wn8), BM=64.
// 2 dispatches total.

#define BROWS 16384
#define DIM 512
#define NL 4
#define OUTSTRIDE (NL * DIM)

#define BM 64
#define BK 32
#define SEG (DIM / BK)        // 16 K-steps per layer

typedef unsigned short ushort_t;
typedef __attribute__((ext_vector_type(8))) short bf16x8;
typedef __attribute__((ext_vector_type(4))) float f32x4;

__device__ inline ushort_t f32_to_bf16(float f) {
    union { float f; uint32_t u; } v; v.f = f;
    uint32_t u = v.u;
    uint32_t r = (u + 0x7fffu + ((u >> 16) & 1u)) >> 16;   // RNE
    return (ushort_t)r;
}

__device__ inline float bf16_bits_to_f32(ushort_t u) {
    union { uint32_t u; float f; } v; v.u = ((uint32_t)u) << 16; return v.f;
}

__device__ inline float bf16_lo(uint32_t p) {
    union { uint32_t u; float f; } v; v.u = p << 16; return v.f;
}
__device__ inline float bf16_hi(uint32_t p) {
    union { uint32_t u; float f; } v; v.u = p & 0xffff0000u; return v.f;
}

__device__ inline float wave_reduce_sum(float v) {
    #pragma unroll
    for (int off = 32; off > 0; off >>= 1) v += __shfl_down(v, off, 64);
    return v;
}

// ---------------------------------------------------------------------------
// prep: W f32 -> bf16 + wsum[l][e] = sum_d W[l][e][d]. 2048 blocks x 256.
// ---------------------------------------------------------------------------
__global__ __launch_bounds__(256) void prep_kernel(
    const float* __restrict__ W, ushort_t* __restrict__ Wb,
    float* __restrict__ wsum)
{
    int row = blockIdx.x;      // l*512 + e
    int t = threadIdx.x;
    const float* wp = W + (size_t)row * DIM;
    float f0 = wp[2 * t], f1 = wp[2 * t + 1];
    ushort_t* wbp = Wb + (size_t)row * DIM;
    wbp[2 * t]     = f32_to_bf16(f0);
    wbp[2 * t + 1] = f32_to_bf16(f1);
    __shared__ float red[4];
    int wave = t >> 6, lane = t & 63;
    float r = wave_reduce_sum(f0 + f1);
    if (lane == 0) red[wave] = r;
    __syncthreads();
    if (t == 0) wsum[row] = red[0] + red[1] + red[2] + red[3];
}

// ---------------------------------------------------------------------------
// fused main kernel: 16 waves (2 wm x 8 wn8), BM=64 rows per block
// ---------------------------------------------------------------------------
__global__ __launch_bounds__(1024)
__attribute__((amdgpu_waves_per_eu(4, 4)))
void cross_kernel(
    const float* __restrict__ x0,
    const ushort_t* __restrict__ Wb,    // [4][512][512] bf16 bits
    const float* __restrict__ bias,     // [4][512]
    const float* __restrict__ wsum,     // [4][512]
    float* __restrict__ out)            // [16384][2048]
{
    // act: [64 rows][512 cols] bf16, 16B-chunk swizzle: chunk kc stored at
    //   elem = row*512 + ((kc ^ (row&15))<<3) + (col&7)
    // sBO: 64KB overlay region:
    //   K-loop:  sB[2][DIM*BK] bf16 double-buffer, pre-swizzled source
    //            (LDS chunk c of row R holds global chunk c ^ (R&3))
    //   epilogue: sOut[32][512] f32 half-tile for coalesced out stores
    __shared__ __align__(16) ushort_t sAct[BM * DIM];             // 64 KB
    __shared__ __align__(16) unsigned char sBO[2 * DIM * BK * 2]; // 64 KB
    __shared__ float sRed[4][8][BM];                               // 8 KB
    __shared__ float sSums[NL][BM];                                // 1 KB
    __shared__ float sCn[BM];

    ushort_t* sB   = (ushort_t*)sBO;    // [2][DIM*BK]
    float*    sOut = (float*)sBO;       // [32][512]

    const int tid  = threadIdx.x;
    const int wave = tid >> 6;     // 0..15
    const int lane = tid & 63;
    const int wm   = wave >> 3;    // 0..1: 32-row half
    const int wn8  = wave & 7;     // 0..7: 64-col eighth
    const int q    = lane >> 4;    // 0..3
    const int rr   = lane & 15;
    const int nlane = lane & 15;
    const int bm   = blockIdx.x * BM;

    // staging: lane covers (srow, chunk lane&3); source chunk pre-swizzled
    const int srow = lane >> 2;          // 0..15

    auto stageB = [&](int s) {    // global step s: layer s>>4, k0 = (s&15)*BK
        const ushort_t* gb = Wb + (size_t)(s >> 4) * (DIM * DIM) + (s & 15) * BK;
        #pragma unroll
        for (int c = 0; c < 2; ++c) {
            int r0 = wave * 32 + c * 16;
            int grow = r0 + srow;
            int gchunk = (lane & 3) ^ (grow & 3);      // pre-swizzled source
            __builtin_amdgcn_global_load_lds(
                (const __attribute__((address_space(1))) void*)(gb + (size_t)grow * DIM + gchunk * 8),
                (__attribute__((address_space(3))) void*)(&sB[(size_t)(s & 1) * (DIM * BK) + r0 * BK]),
                16, 0, 0);
        }
    };

    stageB(0);   // in flight under the x0 phase

    // ---- x0 phase: 4 rows/wave into swizzled act + sums[0] ----
    #pragma unroll
    for (int r4 = 0; r4 < 4; ++r4) {
        int row = wave * 4 + r4;
        const float* xp = x0 + (size_t)(bm + row) * DIM + lane * 8;
        float4 a = ((const float4*)xp)[0];
        float4 b4 = ((const float4*)xp)[1];
        float f[8] = {a.x, a.y, a.z, a.w, b4.x, b4.y, b4.z, b4.w};
        bf16x8 o;
        float s = 0.f;
        #pragma unroll
        for (int i = 0; i < 8; ++i) { o[i] = (short)f32_to_bf16(f[i]); s += f[i]; }
        int kc = lane ^ (row & 15);
        *(bf16x8*)(&sAct[row * DIM + kc * 8]) = o;
        s = wave_reduce_sum(s);
        if (lane == 0) sSums[0][row] = s;
    }
    __syncthreads();

    // register keeps of x0, x1 at this thread's C-positions (packed bf16 pairs)
    uint32_t vk0[16], vk1[16];

    #pragma unroll
    for (int l = 0; l < NL; ++l) {
        f32x4 acc[2][4] = {};

        for (int t = 0; t < SEG; ++t) {
            int s = l * SEG + t;
            // drain my stage(s) (issued one step ago / previous epilogue);
            // after the barrier all stage(s) writes are visible and the other
            // buffer is dead (its readers' MFMAs lgkm-waited pre-barrier).
            asm volatile("s_waitcnt vmcnt(0)" ::: "memory");
            __builtin_amdgcn_s_barrier();
            if (t + 1 < SEG) stageB(s + 1);      // stay within this layer

            bf16x8 af[2], bfr[4];
            #pragma unroll
            for (int mi = 0; mi < 2; ++mi) {
                int row = wm * 32 + mi * 16 + rr;
                int kc = (4 * t + q) ^ (row & 15);
                af[mi] = *(const bf16x8*)(&sAct[row * DIM + kc * 8]);
            }
            #pragma unroll
            for (int ni = 0; ni < 4; ++ni) {
                int erow = wn8 * 64 + ni * 16 + rr;
                int bc = q ^ (erow & 3);               // un-swizzle on read
                bfr[ni] = *(const bf16x8*)(&sB[(size_t)(t & 1) * (DIM * BK) + erow * BK + bc * 8]);
            }
            #pragma unroll
            for (int mi = 0; mi < 2; ++mi)
                #pragma unroll
                for (int ni = 0; ni < 4; ++ni)
                    acc[mi][ni] = __builtin_amdgcn_mfma_f32_16x16x32_bf16(
                        af[mi], bfr[ni], acc[mi][ni], 0, 0, 0);
        }

        // all waves' K-loop sAct/sB reads consumed -> sBO reusable as sOut,
        // sAct safe for in-place writes
        __syncthreads();

        // ---------------- epilogue layer l ----------------
        // C/D layout (verified m89/m91): col = lane&15, row = (lane>>4)*4 + reg
        float ws4[4], bs4[4];
        #pragma unroll
        for (int ni = 0; ni < 4; ++ni) {
            int ng = wn8 * 64 + ni * 16 + nlane;
            ws4[ni] = wsum[l * DIM + ng];
            bs4[ni] = bias[l * DIM + ng];
        }

        #pragma unroll
        for (int mi = 0; mi < 2; ++mi) {
            #pragma unroll
            for (int r = 0; r < 4; ++r) {
                const int mr = mi * 4 + r;
                const int row = wm * 32 + mi * 16 + q * 4 + r;
                const int hrow = wm * 16 + q * 4 + r;    // row within half-tile
                float cc = (l == 0) ? 0.f : sCn[row];
                float vv[4];
                #pragma unroll
                for (int ni = 0; ni < 4; ++ni) {
                    vv[ni] = acc[mi][ni][r] + cc * ws4[ni] + bs4[ni];
                    sOut[hrow * DIM + wn8 * 64 + ni * 16 + nlane] = vv[ni];
                }
                if (l < 3) {
                    // read x_l at my positions from sAct (before overwrite);
                    // doubles as the capture for vk0 (l=0) / vk1 (l=1)
                    ushort_t xl[4];
                    #pragma unroll
                    for (int ni = 0; ni < 4; ++ni) {
                        int cg = wn8 * 8 + ni * 2 + (nlane >> 3);
                        int kc = cg ^ (row & 15);
                        xl[ni] = sAct[row * DIM + kc * 8 + (nlane & 7)];
                    }
                    float vs = 0.f, dc = 0.f;
                    #pragma unroll
                    for (int ni = 0; ni < 4; ++ni) {
                        vs += vv[ni];
                        dc += vv[ni] * bf16_bits_to_f32(xl[ni]);
                    }
                    float d0 = 0.f, d1 = 0.f, d2 = 0.f;
                    if (l == 0) {
                        d0 = dc;
                        #pragma unroll
                        for (int nip = 0; nip < 2; ++nip)
                            vk0[mr * 2 + nip] =
                                (uint32_t)xl[2 * nip] | ((uint32_t)xl[2 * nip + 1] << 16);
                    } else {
                        #pragma unroll
                        for (int nip = 0; nip < 2; ++nip) {
                            uint32_t p = vk0[mr * 2 + nip];
                            d0 += vv[2 * nip] * bf16_lo(p) + vv[2 * nip + 1] * bf16_hi(p);
                        }
                        if (l == 1) {
                            d1 = dc;
                            #pragma unroll
                            for (int nip = 0; nip < 2; ++nip)
                                vk1[mr * 2 + nip] =
                                    (uint32_t)xl[2 * nip] | ((uint32_t)xl[2 * nip + 1] << 16);
                        } else {   // l == 2
                            #pragma unroll
                            for (int nip = 0; nip < 2; ++nip) {
                                uint32_t p = vk1[mr * 2 + nip];
                                d1 += vv[2 * nip] * bf16_lo(p) + vv[2 * nip + 1] * bf16_hi(p);
                            }
                            d2 = dc;
                        }
                    }
                    // in-place act write: x_{l+1}
                    #pragma unroll
                    for (int ni = 0; ni < 4; ++ni) {
                        int cg = wn8 * 8 + ni * 2 + (nlane >> 3);
                        int kc = cg ^ (row & 15);
                        sAct[row * DIM + kc * 8 + (nlane & 7)] = f32_to_bf16(vv[ni]);
                    }
                    // 16-lane reduce
                    #pragma unroll
                    for (int off = 8; off > 0; off >>= 1) {
                        vs += __shfl_xor(vs, off, 64);
                        d0 += __shfl_xor(d0, off, 64);
                        if (l >= 1) d1 += __shfl_xor(d1, off, 64);
                        if (l >= 2) d2 += __shfl_xor(d2, off, 64);
                    }
                    if (nlane == 0) {
                        sRed[0][wn8][row] = vs;
                        sRed[1][wn8][row] = d0;
                        if (l >= 1) sRed[2][wn8][row] = d1;
                        if (l >= 2) sRed[3][wn8][row] = d2;
                    }
                }
            }
            __syncthreads();   // sOut half-tile complete
            // cooperative coalesced copy: 32 rows x 512 f32 = 64KB,
            // 1024 threads x float4 = 16KB/iter, 4 iters, full-line stores
            #pragma unroll
            for (int it = 0; it < 4; ++it) {
                int idx = it * 1024 + tid;        // float4 index 0..4095
                int hr = idx >> 7;                // 0..31
                int c4 = idx & 127;               // 0..127
                int grow = bm + (hr >> 4) * 32 + mi * 16 + (hr & 15);
                float4 v4 = *(const float4*)&sOut[hr * DIM + c4 * 4];
                *(float4*)&out[(size_t)grow * OUTSTRIDE + l * DIM + c4 * 4] = v4;
            }
            __syncthreads();   // sOut free before next half / next stage
        }

        if (l < NL - 1) {
            stageB((l + 1) * SEG);   // first tile of next layer into buf0
            __syncthreads();         // not strictly needed; keeps waves aligned
            if (tid < BM) {
                float vs = 0.f, d0 = 0.f;
                #pragma unroll
                for (int g = 0; g < 8; ++g) { vs += sRed[0][g][tid]; d0 += sRed[1][g][tid]; }
                float c = d0;                                   // j=0: c = 0 + d0 + 0*s0
                if (l >= 1) {
                    float d1 = 0.f;
                    #pragma unroll
                    for (int g = 0; g < 8; ++g) d1 += sRed[2][g][tid];
                    c = c + d1 + c * sSums[1][tid];
                }
                if (l >= 2) {
                    float d2 = 0.f;
                    #pragma unroll
                    for (int g = 0; g < 8; ++g) d2 += sRed[3][g][tid];
                    c = c + d2 + c * sSums[2][tid];
                }
                sCn[tid] = c;
                sSums[l + 1][tid] = vs;
            }
            __syncthreads();
        }
    }
}

// ---------------------------------------------------------------------------
extern "C" void kernel_launch(void* const* d_in, const int* in_sizes, int n_in,
                              void* d_out, int out_size, void* d_ws, size_t ws_size,
                              hipStream_t stream) {
    (void)in_sizes; (void)n_in; (void)out_size; (void)ws_size;
    const float* x0   = (const float*)d_in[0];
    const float* W    = (const float*)d_in[1];
    const float* bias = (const float*)d_in[2];
    float* out = (float*)d_out;

    char* ws = (char*)d_ws;
    // workspace: Wb 4*512*512*2 = 2,097,152 @ 0; wsum 4*512*4 = 8,192 @ 2,097,152
    ushort_t* Wb   = (ushort_t*)ws;
    float*    wsum = (float*)(ws + 2097152);

    prep_kernel<<<NL * DIM, 256, 0, stream>>>(W, Wb, wsum);
    cross_kernel<<<BROWS / BM, 1024, 0, stream>>>(x0, Wb, bias, wsum, out);
}